// Round 1
// baseline (4741.011 us; speedup 1.0000x reference)
//
#include <hip/hip_runtime.h>
#include <hip/hip_bf16.h>

#define BB 2
#define LL 2048
#define DM 256
#define DI 512
#define NST 16
#define RDT 16
#define KC 4
#define NLAY 4
#define DOUT 10
#define XDIM 48            // R + 2N
#define TOK (BB*LL)        // 4096
#define EPSF 1e-5f

__device__ __forceinline__ float sigmoid_f(float x) { return 1.0f / (1.0f + __expf(-x)); }

// ---------------- embedding ----------------
__global__ void embed_kernel(const int* __restrict__ ids, const float* __restrict__ emb,
                             float* __restrict__ hidden) {
  int t = blockIdx.x, d = threadIdx.x;
  hidden[t*DM + d] = emb[ids[t]*DM + d];
}

// ---------------- residual add + layernorm ----------------
__global__ void add_ln_kernel(float* __restrict__ residual, const float* __restrict__ hidden,
                              const float* __restrict__ w, const float* __restrict__ bia,
                              float* __restrict__ out, int first) {
  int t = blockIdx.x, d = threadIdx.x;
  __shared__ float red[DM];
  float r = hidden[t*DM + d];
  if (!first) r += residual[t*DM + d];
  residual[t*DM + d] = r;
  red[d] = r; __syncthreads();
  for (int s = DM/2; s > 0; s >>= 1) { if (d < s) red[d] += red[d+s]; __syncthreads(); }
  float mean = red[0] * (1.0f/DM);
  __syncthreads();
  float diff = r - mean;
  red[d] = diff*diff; __syncthreads();
  for (int s = DM/2; s > 0; s >>= 1) { if (d < s) red[d] += red[d+s]; __syncthreads(); }
  float var = red[0] * (1.0f/DM);
  out[t*DM + d] = diff * rsqrtf(var + EPSF) * w[d] + bia[d];
}

// ---------------- GEMM: C[M,E] = A[M,D] x W[E,D]^T, all dims %64==0 (D%16==0) -------
__global__ __launch_bounds__(256) void gemm_nt64(const float* __restrict__ A,
                                                 const float* __restrict__ W,
                                                 float* __restrict__ C,
                                                 int M, int D, int E) {
  __shared__ __align__(16) float As[16][68];
  __shared__ __align__(16) float Ws[16][68];
  int tid = threadIdx.x;
  int tx = tid & 15, ty = tid >> 4;
  int bm = blockIdx.y * 64, be = blockIdx.x * 64;
  int lr = tid >> 2;          // 0..63
  int lk = (tid & 3) * 4;     // 0,4,8,12
  float acc[4][4] = {};
  for (int k0 = 0; k0 < D; k0 += 16) {
    float4 a4 = *(const float4*)&A[(size_t)(bm + lr)*D + k0 + lk];
    float4 w4 = *(const float4*)&W[(size_t)(be + lr)*D + k0 + lk];
    As[lk+0][lr]=a4.x; As[lk+1][lr]=a4.y; As[lk+2][lr]=a4.z; As[lk+3][lr]=a4.w;
    Ws[lk+0][lr]=w4.x; Ws[lk+1][lr]=w4.y; Ws[lk+2][lr]=w4.z; Ws[lk+3][lr]=w4.w;
    __syncthreads();
    #pragma unroll
    for (int k = 0; k < 16; ++k) {
      float4 av = *(const float4*)&As[k][ty*4];
      float4 wv = *(const float4*)&Ws[k][tx*4];
      float a_[4] = {av.x, av.y, av.z, av.w};
      float w_[4] = {wv.x, wv.y, wv.z, wv.w};
      #pragma unroll
      for (int i = 0; i < 4; ++i)
        #pragma unroll
        for (int j = 0; j < 4; ++j)
          acc[i][j] = fmaf(a_[i], w_[j], acc[i][j]);
    }
    __syncthreads();
  }
  #pragma unroll
  for (int i = 0; i < 4; ++i) {
    float4 o = make_float4(acc[i][0], acc[i][1], acc[i][2], acc[i][3]);
    *(float4*)&C[(size_t)(bm + ty*4 + i)*E + be + tx*4] = o;
  }
}

// ---------------- causal depthwise conv (K=4) + silu ----------------
__global__ void conv_silu_kernel(const float* __restrict__ xz, const float* __restrict__ cw,
                                 const float* __restrict__ cb, float* __restrict__ xc) {
  int idx = blockIdx.x * 256 + threadIdx.x;     // t*DI + d
  int d = idx & (DI-1);
  int t = idx >> 9;
  int l = t & (LL-1);
  float acc = cb[d];
  #pragma unroll
  for (int k = 0; k < KC; ++k) {
    int ll = l + k - (KC-1);
    if (ll >= 0) acc = fmaf(xz[(size_t)(t + k - (KC-1))*(2*DI) + d], cw[d*KC + k], acc);
  }
  xc[idx] = acc * sigmoid_f(acc);
}

// ---------------- x_proj: out[t,e] = dot(xc[t,:], W[e,:]), E=48 ----------------
__global__ void xproj_kernel(const float* __restrict__ xc, const float* __restrict__ W,
                             float* __restrict__ out) {
  int idx = blockIdx.x * 256 + threadIdx.x;     // 0 .. TOK*48
  int t = idx / XDIM, e = idx - t*XDIM;
  const float4* xr = (const float4*)(xc + (size_t)t*DI);
  const float4* wr = (const float4*)(W + (size_t)e*DI);
  float acc = 0.f;
  for (int q = 0; q < DI/4; ++q) {
    float4 a = xr[q], w = wr[q];
    acc = fmaf(a.x, w.x, acc); acc = fmaf(a.y, w.y, acc);
    acc = fmaf(a.z, w.z, acc); acc = fmaf(a.w, w.w, acc);
  }
  out[idx] = acc;
}

// ---------------- dt_proj + softplus ----------------
__global__ void dt_softplus_kernel(const float* __restrict__ xdbl, const float* __restrict__ dtw,
                                   const float* __restrict__ dtb, float* __restrict__ delta) {
  int idx = blockIdx.x * 256 + threadIdx.x;     // t*DI + d
  int d = idx & (DI-1);
  int t = idx >> 9;
  const float4* xr = (const float4*)(xdbl + (size_t)t*XDIM);   // dt = first 16
  const float4* wr = (const float4*)(dtw + (size_t)d*RDT);
  float acc = dtb[d];
  #pragma unroll
  for (int q = 0; q < RDT/4; ++q) {
    float4 a = xr[q], w = wr[q];
    acc = fmaf(a.x, w.x, acc); acc = fmaf(a.y, w.y, acc);
    acc = fmaf(a.z, w.z, acc); acc = fmaf(a.w, w.w, acc);
  }
  // stable softplus = max(x,0) + log1p(exp(-|x|))
  delta[idx] = fmaxf(acc, 0.f) + log1pf(__expf(-fabsf(acc)));
}

// ---------------- selective scan (serial over L, thread per (b,d)) -------------
// fused: y = (scan + Dp*xc) * silu(z)
__global__ __launch_bounds__(256) void scan_kernel(
    const float* __restrict__ delta, const float* __restrict__ xc,
    const float* __restrict__ xdbl, const float* __restrict__ xz,
    const float* __restrict__ A_log, const float* __restrict__ Dp,
    float* __restrict__ y) {
  int b = blockIdx.x >> 1;
  int d = ((blockIdx.x & 1) << 8) + threadIdx.x;
  float A[NST];
  #pragma unroll
  for (int n = 0; n < NST; ++n) A[n] = -expf(A_log[d*NST + n]);
  float Dpv = Dp[d];
  float h[NST];
  #pragma unroll
  for (int n = 0; n < NST; ++n) h[n] = 0.f;
  for (int l = 0; l < LL; ++l) {
    int t = b*LL + l;
    float del = delta[(size_t)t*DI + d];
    float xcv = xc[(size_t)t*DI + d];
    float zv  = xz[(size_t)t*(2*DI) + DI + d];
    const float4* bc = (const float4*)(xdbl + (size_t)t*XDIM + RDT);
    float4 B0 = bc[0], B1 = bc[1], B2 = bc[2], B3 = bc[3];
    float4 C0 = bc[4], C1 = bc[5], C2 = bc[6], C3 = bc[7];
    float Bf[NST] = {B0.x,B0.y,B0.z,B0.w, B1.x,B1.y,B1.z,B1.w,
                     B2.x,B2.y,B2.z,B2.w, B3.x,B3.y,B3.z,B3.w};
    float Cf[NST] = {C0.x,C0.y,C0.z,C0.w, C1.x,C1.y,C1.z,C1.w,
                     C2.x,C2.y,C2.z,C2.w, C3.x,C3.y,C3.z,C3.w};
    float dx = del * xcv;
    float yv = 0.f;
    #pragma unroll
    for (int n = 0; n < NST; ++n) {
      float dA = __expf(del * A[n]);
      h[n] = fmaf(dA, h[n], dx * Bf[n]);
      yv = fmaf(h[n], Cf[n], yv);
    }
    yv = fmaf(Dpv, xcv, yv);
    y[(size_t)t*DI + d] = yv * zv * sigmoid_f(zv);
  }
}

// ---------------- mean-pool over L + decode ----------------
__global__ void pool_decode_kernel(const float* __restrict__ ln, const float* __restrict__ dw,
                                   const float* __restrict__ db, float* __restrict__ out) {
  int b = blockIdx.x, d = threadIdx.x;
  __shared__ float pooled[DM];
  float s = 0.f;
  const float* base = ln + (size_t)b*LL*DM + d;
  for (int l = 0; l < LL; ++l) s += base[(size_t)l*DM];
  pooled[d] = s * (1.0f/LL);
  __syncthreads();
  if (d < DOUT) {
    float acc = db[d];
    for (int m = 0; m < DM; ++m) acc = fmaf(pooled[m], dw[d*DM + m], acc);
    out[b*DOUT + d] = acc;
  }
}

extern "C" void kernel_launch(void* const* d_in, const int* in_sizes, int n_in,
                              void* d_out, int out_size, void* d_ws, size_t ws_size,
                              hipStream_t stream) {
  const int*   ids     = (const int*)d_in[0];
  const float* emb     = (const float*)d_in[1];
  const float* norm_w  = (const float*)d_in[2];
  const float* norm_b  = (const float*)d_in[3];
  const float* in_w    = (const float*)d_in[4];
  const float* conv_w  = (const float*)d_in[5];
  const float* conv_b  = (const float*)d_in[6];
  const float* xp_w    = (const float*)d_in[7];
  const float* dt_w    = (const float*)d_in[8];
  const float* dt_b    = (const float*)d_in[9];
  const float* A_log   = (const float*)d_in[10];
  const float* Dp      = (const float*)d_in[11];
  const float* out_w   = (const float*)d_in[12];
  const float* normf_w = (const float*)d_in[13];
  const float* normf_b = (const float*)d_in[14];
  const float* dec_w   = (const float*)d_in[15];
  const float* dec_b   = (const float*)d_in[16];
  float* out = (float*)d_out;

  float* ws = (float*)d_ws;
  float* hidden   = ws; ws += TOK*DM;
  float* residual = ws; ws += TOK*DM;
  float* hbuf     = ws; ws += TOK*DM;
  float* xzbuf    = ws; ws += (size_t)TOK*2*DI;
  float* xcbuf    = ws; ws += TOK*DI;
  float* xdblbuf  = ws; ws += TOK*XDIM;
  float* deltabuf = ws; ws += TOK*DI;
  float* ybuf     = ws; ws += TOK*DI;

  embed_kernel<<<TOK, DM, 0, stream>>>(ids, emb, hidden);

  for (int i = 0; i < NLAY; ++i) {
    add_ln_kernel<<<TOK, DM, 0, stream>>>(residual, hidden,
                                          norm_w + i*DM, norm_b + i*DM, hbuf, i == 0);
    // in_proj: [TOK,DM] x [2DI,DM]^T -> [TOK,2DI]
    gemm_nt64<<<dim3((2*DI)/64, TOK/64), 256, 0, stream>>>(
        hbuf, in_w + (size_t)i*2*DI*DM, xzbuf, TOK, DM, 2*DI);
    conv_silu_kernel<<<(TOK*DI)/256, 256, 0, stream>>>(
        xzbuf, conv_w + i*DI*KC, conv_b + i*DI, xcbuf);
    xproj_kernel<<<(TOK*XDIM)/256, 256, 0, stream>>>(
        xcbuf, xp_w + (size_t)i*XDIM*DI, xdblbuf);
    dt_softplus_kernel<<<(TOK*DI)/256, 256, 0, stream>>>(
        xdblbuf, dt_w + (size_t)i*DI*RDT, dt_b + i*DI, deltabuf);
    scan_kernel<<<BB*(DI/256), 256, 0, stream>>>(
        deltabuf, xcbuf, xdblbuf, xzbuf, A_log + (size_t)i*DI*NST, Dp + i*DI, ybuf);
    // out_proj: [TOK,DI] x [DM,DI]^T -> [TOK,DM]
    gemm_nt64<<<dim3(DM/64, TOK/64), 256, 0, stream>>>(
        ybuf, out_w + (size_t)i*DM*DI, hidden, TOK, DI, DM);
  }

  add_ln_kernel<<<TOK, DM, 0, stream>>>(residual, hidden, normf_w, normf_b, hbuf, 0);
  pool_decode_kernel<<<BB, DM, 0, stream>>>(hbuf, dec_w, dec_b, out);
}

// Round 2
// 925.921 us; speedup vs baseline: 5.1203x; 5.1203x over previous
//
#include <hip/hip_runtime.h>
#include <hip/hip_bf16.h>

#define BB 2
#define LL 2048
#define DM 256
#define DI 512
#define NST 16
#define RDT 16
#define KC 4
#define NLAY 4
#define DOUT 10
#define XDIM 48            // R + 2N
#define TOK (BB*LL)        // 4096
#define EPSF 1e-5f
#define CHUNK 32
#define NCH (LL/CHUNK)     // 64

__device__ __forceinline__ float sigmoid_f(float x) { return 1.0f / (1.0f + __expf(-x)); }

// ---------------- embedding ----------------
__global__ void embed_kernel(const int* __restrict__ ids, const float* __restrict__ emb,
                             float* __restrict__ hidden) {
  int t = blockIdx.x, d = threadIdx.x;
  hidden[t*DM + d] = emb[ids[t]*DM + d];
}

// ---------------- residual add + layernorm ----------------
__global__ void add_ln_kernel(float* __restrict__ residual, const float* __restrict__ hidden,
                              const float* __restrict__ w, const float* __restrict__ bia,
                              float* __restrict__ out, int first) {
  int t = blockIdx.x, d = threadIdx.x;
  __shared__ float red[DM];
  float r = hidden[t*DM + d];
  if (!first) r += residual[t*DM + d];
  residual[t*DM + d] = r;
  red[d] = r; __syncthreads();
  for (int s = DM/2; s > 0; s >>= 1) { if (d < s) red[d] += red[d+s]; __syncthreads(); }
  float mean = red[0] * (1.0f/DM);
  __syncthreads();
  float diff = r - mean;
  red[d] = diff*diff; __syncthreads();
  for (int s = DM/2; s > 0; s >>= 1) { if (d < s) red[d] += red[d+s]; __syncthreads(); }
  float var = red[0] * (1.0f/DM);
  out[t*DM + d] = diff * rsqrtf(var + EPSF) * w[d] + bia[d];
}

// ---------------- GEMM: C[M,E] = A[M,D] x W[E,D]^T ----------------
__global__ __launch_bounds__(256) void gemm_nt64(const float* __restrict__ A,
                                                 const float* __restrict__ W,
                                                 float* __restrict__ C,
                                                 int M, int D, int E) {
  __shared__ __align__(16) float As[16][68];
  __shared__ __align__(16) float Ws[16][68];
  int tid = threadIdx.x;
  int tx = tid & 15, ty = tid >> 4;
  int bm = blockIdx.y * 64, be = blockIdx.x * 64;
  int lr = tid >> 2;
  int lk = (tid & 3) * 4;
  float acc[4][4] = {};
  for (int k0 = 0; k0 < D; k0 += 16) {
    float4 a4 = *(const float4*)&A[(size_t)(bm + lr)*D + k0 + lk];
    float4 w4 = *(const float4*)&W[(size_t)(be + lr)*D + k0 + lk];
    As[lk+0][lr]=a4.x; As[lk+1][lr]=a4.y; As[lk+2][lr]=a4.z; As[lk+3][lr]=a4.w;
    Ws[lk+0][lr]=w4.x; Ws[lk+1][lr]=w4.y; Ws[lk+2][lr]=w4.z; Ws[lk+3][lr]=w4.w;
    __syncthreads();
    #pragma unroll
    for (int k = 0; k < 16; ++k) {
      float4 av = *(const float4*)&As[k][ty*4];
      float4 wv = *(const float4*)&Ws[k][tx*4];
      float a_[4] = {av.x, av.y, av.z, av.w};
      float w_[4] = {wv.x, wv.y, wv.z, wv.w};
      #pragma unroll
      for (int i = 0; i < 4; ++i)
        #pragma unroll
        for (int j = 0; j < 4; ++j)
          acc[i][j] = fmaf(a_[i], w_[j], acc[i][j]);
    }
    __syncthreads();
  }
  #pragma unroll
  for (int i = 0; i < 4; ++i) {
    float4 o = make_float4(acc[i][0], acc[i][1], acc[i][2], acc[i][3]);
    *(float4*)&C[(size_t)(bm + ty*4 + i)*E + be + tx*4] = o;
  }
}

// ---------------- causal depthwise conv (K=4) + silu ----------------
__global__ void conv_silu_kernel(const float* __restrict__ xz, const float* __restrict__ cw,
                                 const float* __restrict__ cb, float* __restrict__ xc) {
  int idx = blockIdx.x * 256 + threadIdx.x;
  int d = idx & (DI-1);
  int t = idx >> 9;
  int l = t & (LL-1);
  float acc = cb[d];
  #pragma unroll
  for (int k = 0; k < KC; ++k) {
    int ll = l + k - (KC-1);
    if (ll >= 0) acc = fmaf(xz[(size_t)(t + k - (KC-1))*(2*DI) + d], cw[d*KC + k], acc);
  }
  xc[idx] = acc * sigmoid_f(acc);
}

// ---------------- x_proj ----------------
__global__ void xproj_kernel(const float* __restrict__ xc, const float* __restrict__ W,
                             float* __restrict__ out) {
  int idx = blockIdx.x * 256 + threadIdx.x;
  int t = idx / XDIM, e = idx - t*XDIM;
  const float4* xr = (const float4*)(xc + (size_t)t*DI);
  const float4* wr = (const float4*)(W + (size_t)e*DI);
  float acc = 0.f;
  for (int q = 0; q < DI/4; ++q) {
    float4 a = xr[q], w = wr[q];
    acc = fmaf(a.x, w.x, acc); acc = fmaf(a.y, w.y, acc);
    acc = fmaf(a.z, w.z, acc); acc = fmaf(a.w, w.w, acc);
  }
  out[idx] = acc;
}

// ---------------- dt_proj + softplus ----------------
__global__ void dt_softplus_kernel(const float* __restrict__ xdbl, const float* __restrict__ dtw,
                                   const float* __restrict__ dtb, float* __restrict__ delta) {
  int idx = blockIdx.x * 256 + threadIdx.x;
  int d = idx & (DI-1);
  int t = idx >> 9;
  const float4* xr = (const float4*)(xdbl + (size_t)t*XDIM);
  const float4* wr = (const float4*)(dtw + (size_t)d*RDT);
  float acc = dtb[d];
  #pragma unroll
  for (int q = 0; q < RDT/4; ++q) {
    float4 a = xr[q], w = wr[q];
    acc = fmaf(a.x, w.x, acc); acc = fmaf(a.y, w.y, acc);
    acc = fmaf(a.z, w.z, acc); acc = fmaf(a.w, w.w, acc);
  }
  delta[idx] = fmaxf(acc, 0.f) + log1pf(__expf(-fabsf(acc)));
}

// ---------------- chunked selective scan ----------------
// pass1: per-chunk local scan from h=0 -> hloc[b,c,n,d], dsum[b,c,d]
__global__ __launch_bounds__(256) void scan_pass1(
    const float* __restrict__ delta, const float* __restrict__ xc,
    const float* __restrict__ xdbl, const float* __restrict__ A_log,
    float* __restrict__ hloc, float* __restrict__ dsum) {
  __shared__ __align__(16) float Bs[CHUNK][16];
  int bc = blockIdx.x >> 1;                      // b*NCH + c
  int d  = ((blockIdx.x & 1) << 8) + threadIdx.x;
  int b = bc >> 6, c = bc & (NCH-1);
  int t0 = b*LL + c*CHUNK;
  int tid = threadIdx.x;
  if (tid < CHUNK*4) {
    int row = tid >> 2, q = tid & 3;
    *(float4*)&Bs[row][q*4] = *(const float4*)&xdbl[(size_t)(t0+row)*XDIM + RDT + q*4];
  }
  __syncthreads();
  float A[NST];
  #pragma unroll
  for (int n = 0; n < NST; ++n) A[n] = -__expf(A_log[d*NST + n]);
  float h[NST];
  #pragma unroll
  for (int n = 0; n < NST; ++n) h[n] = 0.f;
  float ds = 0.f;
  for (int l = 0; l < CHUNK; ++l) {
    int t = t0 + l;
    float del = delta[(size_t)t*DI + d];
    float xcv = xc[(size_t)t*DI + d];
    ds += del;
    float dx = del * xcv;
    #pragma unroll
    for (int n = 0; n < NST; ++n)
      h[n] = fmaf(__expf(del * A[n]), h[n], dx * Bs[l][n]);
  }
  #pragma unroll
  for (int n = 0; n < NST; ++n)
    hloc[((size_t)bc*NST + n)*DI + d] = h[n];
  dsum[(size_t)bc*DI + d] = ds;
}

// pass2: inter-chunk combine, serial over NCH chunks per (b,d,n)
__global__ __launch_bounds__(256) void scan_pass2(
    const float* __restrict__ hloc, const float* __restrict__ dsum,
    const float* __restrict__ A_log, float* __restrict__ hinit) {
  int g = blockIdx.x*256 + threadIdx.x;          // (b*NST + n)*DI + d
  int d = g & (DI-1);
  int n = (g >> 9) & (NST-1);
  int b = g >> 13;
  float A = -__expf(A_log[d*NST + n]);
  float hc = 0.f;
  for (int c = 0; c < NCH; ++c) {
    size_t bc = (size_t)(b*NCH + c);
    hinit[(bc*NST + n)*DI + d] = hc;
    float P = __expf(A * dsum[bc*DI + d]);
    hc = fmaf(P, hc, hloc[(bc*NST + n)*DI + d]);
  }
}

// pass3: replay chunk from hinit, produce y = (scan + Dp*xc)*silu(z)
__global__ __launch_bounds__(256) void scan_pass3(
    const float* __restrict__ delta, const float* __restrict__ xc,
    const float* __restrict__ xdbl, const float* __restrict__ xz,
    const float* __restrict__ A_log, const float* __restrict__ Dp,
    const float* __restrict__ hinit, float* __restrict__ y) {
  __shared__ __align__(16) float BCs[CHUNK][32];
  int bc = blockIdx.x >> 1;
  int d  = ((blockIdx.x & 1) << 8) + threadIdx.x;
  int b = bc >> 6, c = bc & (NCH-1);
  int t0 = b*LL + c*CHUNK;
  int tid = threadIdx.x;
  {
    int row = tid >> 3, q = tid & 7;             // 32 rows x 8 quads
    *(float4*)&BCs[row][q*4] = *(const float4*)&xdbl[(size_t)(t0+row)*XDIM + RDT + q*4];
  }
  __syncthreads();
  float A[NST];
  #pragma unroll
  for (int n = 0; n < NST; ++n) A[n] = -__expf(A_log[d*NST + n]);
  float h[NST];
  #pragma unroll
  for (int n = 0; n < NST; ++n) h[n] = hinit[((size_t)bc*NST + n)*DI + d];
  float Dpv = Dp[d];
  for (int l = 0; l < CHUNK; ++l) {
    int t = t0 + l;
    float del = delta[(size_t)t*DI + d];
    float xcv = xc[(size_t)t*DI + d];
    float zv  = xz[(size_t)t*(2*DI) + DI + d];
    float dx = del * xcv;
    float yv = 0.f;
    #pragma unroll
    for (int n = 0; n < NST; ++n) {
      h[n] = fmaf(__expf(del * A[n]), h[n], dx * BCs[l][n]);
      yv = fmaf(h[n], BCs[l][16 + n], yv);
    }
    yv = fmaf(Dpv, xcv, yv);
    y[(size_t)t*DI + d] = yv * zv * sigmoid_f(zv);
  }
}

// ---------------- mean-pool over L + decode ----------------
__global__ void pool_decode_kernel(const float* __restrict__ ln, const float* __restrict__ dw,
                                   const float* __restrict__ db, float* __restrict__ out) {
  int b = blockIdx.x, d = threadIdx.x;
  __shared__ float pooled[DM];
  float s = 0.f;
  const float* base = ln + (size_t)b*LL*DM + d;
  for (int l = 0; l < LL; ++l) s += base[(size_t)l*DM];
  pooled[d] = s * (1.0f/LL);
  __syncthreads();
  if (d < DOUT) {
    float acc = db[d];
    for (int m = 0; m < DM; ++m) acc = fmaf(pooled[m], dw[d*DM + m], acc);
    out[b*DOUT + d] = acc;
  }
}

extern "C" void kernel_launch(void* const* d_in, const int* in_sizes, int n_in,
                              void* d_out, int out_size, void* d_ws, size_t ws_size,
                              hipStream_t stream) {
  const int*   ids     = (const int*)d_in[0];
  const float* emb     = (const float*)d_in[1];
  const float* norm_w  = (const float*)d_in[2];
  const float* norm_b  = (const float*)d_in[3];
  const float* in_w    = (const float*)d_in[4];
  const float* conv_w  = (const float*)d_in[5];
  const float* conv_b  = (const float*)d_in[6];
  const float* xp_w    = (const float*)d_in[7];
  const float* dt_w    = (const float*)d_in[8];
  const float* dt_b    = (const float*)d_in[9];
  const float* A_log   = (const float*)d_in[10];
  const float* Dp      = (const float*)d_in[11];
  const float* out_w   = (const float*)d_in[12];
  const float* normf_w = (const float*)d_in[13];
  const float* normf_b = (const float*)d_in[14];
  const float* dec_w   = (const float*)d_in[15];
  const float* dec_b   = (const float*)d_in[16];
  float* out = (float*)d_out;

  float* ws = (float*)d_ws;
  float* hidden   = ws; ws += TOK*DM;
  float* residual = ws; ws += TOK*DM;
  float* hbuf     = ws; ws += TOK*DM;
  float* xzbuf    = ws; ws += (size_t)TOK*2*DI;
  float* xcbuf    = ws; ws += TOK*DI;
  float* xdblbuf  = ws; ws += TOK*XDIM;
  float* deltabuf = ws; ws += TOK*DI;
  float* ybuf     = ws; ws += TOK*DI;
  float* hlocbuf  = ws; ws += (size_t)BB*NCH*NST*DI;
  float* hinitbuf = ws; ws += (size_t)BB*NCH*NST*DI;
  float* dsumbuf  = ws; ws += (size_t)BB*NCH*DI;

  embed_kernel<<<TOK, DM, 0, stream>>>(ids, emb, hidden);

  for (int i = 0; i < NLAY; ++i) {
    add_ln_kernel<<<TOK, DM, 0, stream>>>(residual, hidden,
                                          norm_w + i*DM, norm_b + i*DM, hbuf, i == 0);
    gemm_nt64<<<dim3((2*DI)/64, TOK/64), 256, 0, stream>>>(
        hbuf, in_w + (size_t)i*2*DI*DM, xzbuf, TOK, DM, 2*DI);
    conv_silu_kernel<<<(TOK*DI)/256, 256, 0, stream>>>(
        xzbuf, conv_w + i*DI*KC, conv_b + i*DI, xcbuf);
    xproj_kernel<<<(TOK*XDIM)/256, 256, 0, stream>>>(
        xcbuf, xp_w + (size_t)i*XDIM*DI, xdblbuf);
    dt_softplus_kernel<<<(TOK*DI)/256, 256, 0, stream>>>(
        xdblbuf, dt_w + (size_t)i*DI*RDT, dt_b + i*DI, deltabuf);
    scan_pass1<<<BB*NCH*(DI/256), 256, 0, stream>>>(
        deltabuf, xcbuf, xdblbuf, A_log + (size_t)i*DI*NST, hlocbuf, dsumbuf);
    scan_pass2<<<(BB*NST*DI)/256, 256, 0, stream>>>(
        hlocbuf, dsumbuf, A_log + (size_t)i*DI*NST, hinitbuf);
    scan_pass3<<<BB*NCH*(DI/256), 256, 0, stream>>>(
        deltabuf, xcbuf, xdblbuf, xzbuf, A_log + (size_t)i*DI*NST, Dp + i*DI,
        hinitbuf, ybuf);
    gemm_nt64<<<dim3(DM/64, TOK/64), 256, 0, stream>>>(
        ybuf, out_w + (size_t)i*DM*DI, hidden, TOK, DI, DM);
  }

  add_ln_kernel<<<TOK, DM, 0, stream>>>(residual, hidden, normf_w, normf_b, hbuf, 0);
  pool_decode_kernel<<<BB, DM, 0, stream>>>(hbuf, dec_w, dec_b, out);
}

// Round 3
// 804.816 us; speedup vs baseline: 5.8908x; 1.1505x over previous
//
#include <hip/hip_runtime.h>
#include <hip/hip_bf16.h>

#define BB 2
#define LL 2048
#define DM 256
#define DI 512
#define NST 16
#define RDT 16
#define KC 4
#define NLAY 4
#define DOUT 10
#define XDIM 48            // R + 2N
#define TOK (BB*LL)        // 4096
#define EPSF 1e-5f
#define CHUNK 32
#define NCH (LL/CHUNK)     // 64

__device__ __forceinline__ float sigmoid_f(float x) { return 1.0f / (1.0f + __expf(-x)); }

// ---------------- embedding ----------------
__global__ void embed_kernel(const int* __restrict__ ids, const float* __restrict__ emb,
                             float* __restrict__ hidden) {
  int t = blockIdx.x, d = threadIdx.x;
  hidden[t*DM + d] = emb[ids[t]*DM + d];
}

// ---------------- residual add + layernorm (wave-shuffle reduction) ----------------
__global__ void add_ln_kernel(float* __restrict__ residual, const float* __restrict__ hidden,
                              const float* __restrict__ w, const float* __restrict__ bia,
                              float* __restrict__ out, int first) {
  int t = blockIdx.x, d = threadIdx.x;
  __shared__ float ws8[8];
  float r = hidden[t*DM + d];
  if (!first) r += residual[t*DM + d];
  residual[t*DM + d] = r;
  float s = r;
  #pragma unroll
  for (int o = 32; o; o >>= 1) s += __shfl_down(s, o);
  if ((d & 63) == 0) ws8[d >> 6] = s;
  __syncthreads();
  float mean = (ws8[0] + ws8[1] + ws8[2] + ws8[3]) * (1.0f/DM);
  float diff = r - mean;
  float q = diff * diff;
  #pragma unroll
  for (int o = 32; o; o >>= 1) q += __shfl_down(q, o);
  if ((d & 63) == 0) ws8[4 + (d >> 6)] = q;
  __syncthreads();
  float var = (ws8[4] + ws8[5] + ws8[6] + ws8[7]) * (1.0f/DM);
  out[t*DM + d] = diff * rsqrtf(var + EPSF) * w[d] + bia[d];
}

// ---------------- GEMM 64x64 tile: C[M,E] = A[M,D] x W[E,D]^T ----------------
__global__ __launch_bounds__(256) void gemm_nt64(const float* __restrict__ A,
                                                 const float* __restrict__ W,
                                                 float* __restrict__ C,
                                                 int M, int D, int E) {
  __shared__ __align__(16) float As[16][68];
  __shared__ __align__(16) float Ws[16][68];
  int tid = threadIdx.x;
  int tx = tid & 15, ty = tid >> 4;
  int bm = blockIdx.y * 64, be = blockIdx.x * 64;
  int lr = tid >> 2;
  int lk = (tid & 3) * 4;
  float acc[4][4] = {};
  for (int k0 = 0; k0 < D; k0 += 16) {
    float4 a4 = *(const float4*)&A[(size_t)(bm + lr)*D + k0 + lk];
    float4 w4 = *(const float4*)&W[(size_t)(be + lr)*D + k0 + lk];
    As[lk+0][lr]=a4.x; As[lk+1][lr]=a4.y; As[lk+2][lr]=a4.z; As[lk+3][lr]=a4.w;
    Ws[lk+0][lr]=w4.x; Ws[lk+1][lr]=w4.y; Ws[lk+2][lr]=w4.z; Ws[lk+3][lr]=w4.w;
    __syncthreads();
    #pragma unroll
    for (int k = 0; k < 16; ++k) {
      float4 av = *(const float4*)&As[k][ty*4];
      float4 wv = *(const float4*)&Ws[k][tx*4];
      float a_[4] = {av.x, av.y, av.z, av.w};
      float w_[4] = {wv.x, wv.y, wv.z, wv.w};
      #pragma unroll
      for (int i = 0; i < 4; ++i)
        #pragma unroll
        for (int j = 0; j < 4; ++j)
          acc[i][j] = fmaf(a_[i], w_[j], acc[i][j]);
    }
    __syncthreads();
  }
  #pragma unroll
  for (int i = 0; i < 4; ++i) {
    float4 o = make_float4(acc[i][0], acc[i][1], acc[i][2], acc[i][3]);
    *(float4*)&C[(size_t)(bm + ty*4 + i)*E + be + tx*4] = o;
  }
}

// ---------------- GEMM 128x128 tile, 8x8 acc/thread (for in_proj) ----------------
__global__ __launch_bounds__(256) void gemm_nt128(const float* __restrict__ A,
                                                  const float* __restrict__ W,
                                                  float* __restrict__ C,
                                                  int D, int E) {
  __shared__ float As[16][132];   // [k][m], row = 528 B (16B-aligned)
  __shared__ float Ws[16][132];
  int tid = threadIdx.x;
  int tx = tid & 15, ty = tid >> 4;
  int bm = blockIdx.y * 128, be = blockIdx.x * 128;
  int m0 = ty * 8, e0 = tx * 8;
  int lr = tid >> 1;              // 0..127
  int lc = (tid & 1) * 8;         // 0 or 8
  float acc[8][8] = {};
  for (int k0 = 0; k0 < D; k0 += 16) {
    float4 a0 = *(const float4*)&A[(size_t)(bm + lr)*D + k0 + lc];
    float4 a1 = *(const float4*)&A[(size_t)(bm + lr)*D + k0 + lc + 4];
    float4 w0 = *(const float4*)&W[(size_t)(be + lr)*D + k0 + lc];
    float4 w1 = *(const float4*)&W[(size_t)(be + lr)*D + k0 + lc + 4];
    As[lc+0][lr]=a0.x; As[lc+1][lr]=a0.y; As[lc+2][lr]=a0.z; As[lc+3][lr]=a0.w;
    As[lc+4][lr]=a1.x; As[lc+5][lr]=a1.y; As[lc+6][lr]=a1.z; As[lc+7][lr]=a1.w;
    Ws[lc+0][lr]=w0.x; Ws[lc+1][lr]=w0.y; Ws[lc+2][lr]=w0.z; Ws[lc+3][lr]=w0.w;
    Ws[lc+4][lr]=w1.x; Ws[lc+5][lr]=w1.y; Ws[lc+6][lr]=w1.z; Ws[lc+7][lr]=w1.w;
    __syncthreads();
    #pragma unroll
    for (int k = 0; k < 16; ++k) {
      float4 av0 = *(const float4*)&As[k][m0];
      float4 av1 = *(const float4*)&As[k][m0+4];
      float4 wv0 = *(const float4*)&Ws[k][e0];
      float4 wv1 = *(const float4*)&Ws[k][e0+4];
      float a_[8] = {av0.x,av0.y,av0.z,av0.w, av1.x,av1.y,av1.z,av1.w};
      float w_[8] = {wv0.x,wv0.y,wv0.z,wv0.w, wv1.x,wv1.y,wv1.z,wv1.w};
      #pragma unroll
      for (int i = 0; i < 8; ++i)
        #pragma unroll
        for (int j = 0; j < 8; ++j)
          acc[i][j] = fmaf(a_[i], w_[j], acc[i][j]);
    }
    __syncthreads();
  }
  #pragma unroll
  for (int i = 0; i < 8; ++i) {
    *(float4*)&C[(size_t)(bm + m0 + i)*E + be + e0]     = make_float4(acc[i][0],acc[i][1],acc[i][2],acc[i][3]);
    *(float4*)&C[(size_t)(bm + m0 + i)*E + be + e0 + 4] = make_float4(acc[i][4],acc[i][5],acc[i][6],acc[i][7]);
  }
}

// ---------------- causal depthwise conv (K=4) + silu ----------------
__global__ void conv_silu_kernel(const float* __restrict__ xz, const float* __restrict__ cw,
                                 const float* __restrict__ cb, float* __restrict__ xc) {
  int idx = blockIdx.x * 256 + threadIdx.x;
  int d = idx & (DI-1);
  int t = idx >> 9;
  int l = t & (LL-1);
  float acc = cb[d];
  #pragma unroll
  for (int k = 0; k < KC; ++k) {
    int ll = l + k - (KC-1);
    if (ll >= 0) acc = fmaf(xz[(size_t)(t + k - (KC-1))*(2*DI) + d], cw[d*KC + k], acc);
  }
  xc[idx] = acc * sigmoid_f(acc);
}

// ---------------- x_proj as tiled GEMM: out[t,e] = xc[t,:] . W[e,:], E=48 ------
// grid: TOK/64 blocks; tile M=64, K-step 32
__global__ __launch_bounds__(256) void xproj_gemm(const float* __restrict__ xc,
                                                  const float* __restrict__ W,
                                                  float* __restrict__ out) {
  __shared__ float Xs[64][36];   // [t][k], row 144 B (16B-aligned)
  __shared__ float Ws[48][36];   // [e][k]
  int tid = threadIdx.x;
  int tx = tid & 15, ty = tid >> 4;
  int e0 = tx * 3, t0 = ty * 4;
  int bm = blockIdx.x * 64;
  int lr = tid >> 2;             // 0..63
  int lc = (tid & 3) * 8;        // 0,8,16,24
  int we = tid >> 2;             // for W staging (0..63, use <48)
  float acc[4][3] = {};
  for (int k0 = 0; k0 < DI; k0 += 32) {
    float4 x0 = *(const float4*)&xc[(size_t)(bm + lr)*DI + k0 + lc];
    float4 x1 = *(const float4*)&xc[(size_t)(bm + lr)*DI + k0 + lc + 4];
    *(float4*)&Xs[lr][lc]     = x0;
    *(float4*)&Xs[lr][lc + 4] = x1;
    if (we < 48) {
      float4 w0 = *(const float4*)&W[(size_t)we*DI + k0 + lc];
      float4 w1 = *(const float4*)&W[(size_t)we*DI + k0 + lc + 4];
      *(float4*)&Ws[we][lc]     = w0;
      *(float4*)&Ws[we][lc + 4] = w1;
    }
    __syncthreads();
    #pragma unroll
    for (int kk = 0; kk < 32; kk += 4) {
      float4 xv[4], wv[3];
      #pragma unroll
      for (int i = 0; i < 4; ++i) xv[i] = *(const float4*)&Xs[t0+i][kk];
      #pragma unroll
      for (int j = 0; j < 3; ++j) wv[j] = *(const float4*)&Ws[e0+j][kk];
      #pragma unroll
      for (int i = 0; i < 4; ++i)
        #pragma unroll
        for (int j = 0; j < 3; ++j) {
          acc[i][j] = fmaf(xv[i].x, wv[j].x, acc[i][j]);
          acc[i][j] = fmaf(xv[i].y, wv[j].y, acc[i][j]);
          acc[i][j] = fmaf(xv[i].z, wv[j].z, acc[i][j]);
          acc[i][j] = fmaf(xv[i].w, wv[j].w, acc[i][j]);
        }
    }
    __syncthreads();
  }
  #pragma unroll
  for (int i = 0; i < 4; ++i)
    #pragma unroll
    for (int j = 0; j < 3; ++j)
      out[(size_t)(bm + t0 + i)*XDIM + e0 + j] = acc[i][j];
}

// ---------------- dt_proj + softplus ----------------
__global__ void dt_softplus_kernel(const float* __restrict__ xdbl, const float* __restrict__ dtw,
                                   const float* __restrict__ dtb, float* __restrict__ delta) {
  int idx = blockIdx.x * 256 + threadIdx.x;
  int d = idx & (DI-1);
  int t = idx >> 9;
  const float4* xr = (const float4*)(xdbl + (size_t)t*XDIM);
  const float4* wr = (const float4*)(dtw + (size_t)d*RDT);
  float acc = dtb[d];
  #pragma unroll
  for (int q = 0; q < RDT/4; ++q) {
    float4 a = xr[q], w = wr[q];
    acc = fmaf(a.x, w.x, acc); acc = fmaf(a.y, w.y, acc);
    acc = fmaf(a.z, w.z, acc); acc = fmaf(a.w, w.w, acc);
  }
  delta[idx] = fmaxf(acc, 0.f) + log1pf(__expf(-fabsf(acc)));
}

// ---------------- chunked selective scan ----------------
__global__ __launch_bounds__(256) void scan_pass1(
    const float* __restrict__ delta, const float* __restrict__ xc,
    const float* __restrict__ xdbl, const float* __restrict__ A_log,
    float* __restrict__ hloc, float* __restrict__ dsum) {
  __shared__ __align__(16) float Bs[CHUNK][16];
  int bc = blockIdx.x >> 1;
  int d  = ((blockIdx.x & 1) << 8) + threadIdx.x;
  int b = bc >> 6, c = bc & (NCH-1);
  int t0 = b*LL + c*CHUNK;
  int tid = threadIdx.x;
  if (tid < CHUNK*4) {
    int row = tid >> 2, q = tid & 3;
    *(float4*)&Bs[row][q*4] = *(const float4*)&xdbl[(size_t)(t0+row)*XDIM + RDT + q*4];
  }
  __syncthreads();
  float A[NST];
  #pragma unroll
  for (int n = 0; n < NST; ++n) A[n] = -__expf(A_log[d*NST + n]);
  float h[NST];
  #pragma unroll
  for (int n = 0; n < NST; ++n) h[n] = 0.f;
  float ds = 0.f;
  for (int l = 0; l < CHUNK; ++l) {
    int t = t0 + l;
    float del = delta[(size_t)t*DI + d];
    float xcv = xc[(size_t)t*DI + d];
    ds += del;
    float dx = del * xcv;
    #pragma unroll
    for (int n = 0; n < NST; ++n)
      h[n] = fmaf(__expf(del * A[n]), h[n], dx * Bs[l][n]);
  }
  #pragma unroll
  for (int n = 0; n < NST; ++n)
    hloc[((size_t)bc*NST + n)*DI + d] = h[n];
  dsum[(size_t)bc*DI + d] = ds;
}

__global__ __launch_bounds__(256) void scan_pass2(
    const float* __restrict__ hloc, const float* __restrict__ dsum,
    const float* __restrict__ A_log, float* __restrict__ hinit) {
  int g = blockIdx.x*256 + threadIdx.x;
  int d = g & (DI-1);
  int n = (g >> 9) & (NST-1);
  int b = g >> 13;
  float A = -__expf(A_log[d*NST + n]);
  float hc = 0.f;
  for (int c = 0; c < NCH; ++c) {
    size_t bc = (size_t)(b*NCH + c);
    hinit[(bc*NST + n)*DI + d] = hc;
    float P = __expf(A * dsum[bc*DI + d]);
    hc = fmaf(P, hc, hloc[(bc*NST + n)*DI + d]);
  }
}

__global__ __launch_bounds__(256) void scan_pass3(
    const float* __restrict__ delta, const float* __restrict__ xc,
    const float* __restrict__ xdbl, const float* __restrict__ xz,
    const float* __restrict__ A_log, const float* __restrict__ Dp,
    const float* __restrict__ hinit, float* __restrict__ y) {
  __shared__ __align__(16) float BCs[CHUNK][32];
  int bc = blockIdx.x >> 1;
  int d  = ((blockIdx.x & 1) << 8) + threadIdx.x;
  int b = bc >> 6, c = bc & (NCH-1);
  int t0 = b*LL + c*CHUNK;
  int tid = threadIdx.x;
  {
    int row = tid >> 3, q = tid & 7;
    *(float4*)&BCs[row][q*4] = *(const float4*)&xdbl[(size_t)(t0+row)*XDIM + RDT + q*4];
  }
  __syncthreads();
  float A[NST];
  #pragma unroll
  for (int n = 0; n < NST; ++n) A[n] = -__expf(A_log[d*NST + n]);
  float h[NST];
  #pragma unroll
  for (int n = 0; n < NST; ++n) h[n] = hinit[((size_t)bc*NST + n)*DI + d];
  float Dpv = Dp[d];
  for (int l = 0; l < CHUNK; ++l) {
    int t = t0 + l;
    float del = delta[(size_t)t*DI + d];
    float xcv = xc[(size_t)t*DI + d];
    float zv  = xz[(size_t)t*(2*DI) + DI + d];
    float dx = del * xcv;
    float yv = 0.f;
    #pragma unroll
    for (int n = 0; n < NST; ++n) {
      h[n] = fmaf(__expf(del * A[n]), h[n], dx * BCs[l][n]);
      yv = fmaf(h[n], BCs[l][16 + n], yv);
    }
    yv = fmaf(Dpv, xcv, yv);
    y[(size_t)t*DI + d] = yv * zv * sigmoid_f(zv);
  }
}

// ---------------- pool stage 1: partial sums over L ----------------
__global__ void pool1_kernel(const float* __restrict__ ln, float* __restrict__ part) {
  int blk = blockIdx.x;             // b*16 + c
  int b = blk >> 4, c = blk & 15;
  int d = threadIdx.x;
  const float* base = ln + (size_t)b*LL*DM + (size_t)c*128*DM + d;
  float s = 0.f;
  #pragma unroll 8
  for (int l = 0; l < 128; ++l) s += base[(size_t)l*DM];
  part[(size_t)blk*DM + d] = s;
}

// ---------------- pool stage 2 + decode ----------------
__global__ void pool_decode_kernel(const float* __restrict__ part, const float* __restrict__ dw,
                                   const float* __restrict__ db, float* __restrict__ out) {
  int b = blockIdx.x, d = threadIdx.x;
  __shared__ float pooled[DM];
  float s = 0.f;
  #pragma unroll
  for (int c = 0; c < 16; ++c) s += part[(size_t)(b*16 + c)*DM + d];
  pooled[d] = s * (1.0f/LL);
  __syncthreads();
  if (d < DOUT) {
    float acc = db[d];
    for (int m = 0; m < DM; ++m) acc = fmaf(pooled[m], dw[d*DM + m], acc);
    out[b*DOUT + d] = acc;
  }
}

extern "C" void kernel_launch(void* const* d_in, const int* in_sizes, int n_in,
                              void* d_out, int out_size, void* d_ws, size_t ws_size,
                              hipStream_t stream) {
  const int*   ids     = (const int*)d_in[0];
  const float* emb     = (const float*)d_in[1];
  const float* norm_w  = (const float*)d_in[2];
  const float* norm_b  = (const float*)d_in[3];
  const float* in_w    = (const float*)d_in[4];
  const float* conv_w  = (const float*)d_in[5];
  const float* conv_b  = (const float*)d_in[6];
  const float* xp_w    = (const float*)d_in[7];
  const float* dt_w    = (const float*)d_in[8];
  const float* dt_b    = (const float*)d_in[9];
  const float* A_log   = (const float*)d_in[10];
  const float* Dp      = (const float*)d_in[11];
  const float* out_w   = (const float*)d_in[12];
  const float* normf_w = (const float*)d_in[13];
  const float* normf_b = (const float*)d_in[14];
  const float* dec_w   = (const float*)d_in[15];
  const float* dec_b   = (const float*)d_in[16];
  float* out = (float*)d_out;

  float* ws = (float*)d_ws;
  float* hidden   = ws; ws += TOK*DM;
  float* residual = ws; ws += TOK*DM;
  float* hbuf     = ws; ws += TOK*DM;
  float* xzbuf    = ws; ws += (size_t)TOK*2*DI;
  float* xcbuf    = ws; ws += TOK*DI;
  float* xdblbuf  = ws; ws += TOK*XDIM;
  float* deltabuf = ws; ws += TOK*DI;
  float* ybuf     = ws; ws += TOK*DI;
  float* hlocbuf  = ws; ws += (size_t)BB*NCH*NST*DI;
  float* hinitbuf = ws; ws += (size_t)BB*NCH*NST*DI;
  float* dsumbuf  = ws; ws += (size_t)BB*NCH*DI;
  float* partbuf  = ws; ws += (size_t)BB*16*DM;

  embed_kernel<<<TOK, DM, 0, stream>>>(ids, emb, hidden);

  for (int i = 0; i < NLAY; ++i) {
    add_ln_kernel<<<TOK, DM, 0, stream>>>(residual, hidden,
                                          norm_w + i*DM, norm_b + i*DM, hbuf, i == 0);
    // in_proj: [TOK,DM] x [2DI,DM]^T -> [TOK,2DI]
    gemm_nt128<<<dim3((2*DI)/128, TOK/128), 256, 0, stream>>>(
        hbuf, in_w + (size_t)i*2*DI*DM, xzbuf, DM, 2*DI);
    conv_silu_kernel<<<(TOK*DI)/256, 256, 0, stream>>>(
        xzbuf, conv_w + i*DI*KC, conv_b + i*DI, xcbuf);
    xproj_gemm<<<TOK/64, 256, 0, stream>>>(
        xcbuf, xp_w + (size_t)i*XDIM*DI, xdblbuf);
    dt_softplus_kernel<<<(TOK*DI)/256, 256, 0, stream>>>(
        xdblbuf, dt_w + (size_t)i*DI*RDT, dt_b + i*DI, deltabuf);
    scan_pass1<<<BB*NCH*(DI/256), 256, 0, stream>>>(
        deltabuf, xcbuf, xdblbuf, A_log + (size_t)i*DI*NST, hlocbuf, dsumbuf);
    scan_pass2<<<(BB*NST*DI)/256, 256, 0, stream>>>(
        hlocbuf, dsumbuf, A_log + (size_t)i*DI*NST, hinitbuf);
    scan_pass3<<<BB*NCH*(DI/256), 256, 0, stream>>>(
        deltabuf, xcbuf, xdblbuf, xzbuf, A_log + (size_t)i*DI*NST, Dp + i*DI,
        hinitbuf, ybuf);
    // out_proj: [TOK,DI] x [DM,DI]^T -> [TOK,DM]
    gemm_nt64<<<dim3(DM/64, TOK/64), 256, 0, stream>>>(
        ybuf, out_w + (size_t)i*DM*DI, hidden, TOK, DI, DM);
  }

  add_ln_kernel<<<TOK, DM, 0, stream>>>(residual, hidden, normf_w, normf_b, hbuf, 0);
  pool1_kernel<<<BB*16, DM, 0, stream>>>(hbuf, partbuf);
  pool_decode_kernel<<<BB, DM, 0, stream>>>(partbuf, dec_w, dec_b, out);
}

// Round 4
// 709.085 us; speedup vs baseline: 6.6861x; 1.1350x over previous
//
#include <hip/hip_runtime.h>
#include <hip/hip_bf16.h>

#define BB 2
#define LL 2048
#define DM 256
#define DI 512
#define NST 16
#define RDT 16
#define KC 4
#define NLAY 4
#define DOUT 10
#define XDIM 48            // R + 2N
#define TOK (BB*LL)        // 4096
#define EPSF 1e-5f
#define CHUNK 32
#define NCH (LL/CHUNK)     // 64

__device__ __forceinline__ float sigmoid_f(float x) { return 1.0f / (1.0f + __expf(-x)); }

// ---------------- embedding ----------------
__global__ void embed_kernel(const int* __restrict__ ids, const float* __restrict__ emb,
                             float* __restrict__ hidden) {
  int t = blockIdx.x, d = threadIdx.x;
  hidden[t*DM + d] = emb[ids[t]*DM + d];
}

// ---------------- residual add + layernorm (wave-shuffle reduction) ----------------
__global__ void add_ln_kernel(float* __restrict__ residual, const float* __restrict__ hidden,
                              const float* __restrict__ w, const float* __restrict__ bia,
                              float* __restrict__ out, int first) {
  int t = blockIdx.x, d = threadIdx.x;
  __shared__ float ws8[8];
  float r = hidden[t*DM + d];
  if (!first) r += residual[t*DM + d];
  residual[t*DM + d] = r;
  float s = r;
  #pragma unroll
  for (int o = 32; o; o >>= 1) s += __shfl_down(s, o);
  if ((d & 63) == 0) ws8[d >> 6] = s;
  __syncthreads();
  float mean = (ws8[0] + ws8[1] + ws8[2] + ws8[3]) * (1.0f/DM);
  float diff = r - mean;
  float q = diff * diff;
  #pragma unroll
  for (int o = 32; o; o >>= 1) q += __shfl_down(q, o);
  if ((d & 63) == 0) ws8[4 + (d >> 6)] = q;
  __syncthreads();
  float var = (ws8[4] + ws8[5] + ws8[6] + ws8[7]) * (1.0f/DM);
  out[t*DM + d] = diff * rsqrtf(var + EPSF) * w[d] + bia[d];
}

// ---------------- GEMM 128(M)x64(E), K-step 32, conflict-free ----------------
// C[M,E] = A[M,D] x W[E,D]^T.  grid = (E/64, M/128), 256 thr.
// per-thread acc 8x4: rows {ty*4+i, 64+ty*4+i}, cols tx*4+j.
__global__ __launch_bounds__(256, 2) void gemm_in(const float* __restrict__ A,
                                                  const float* __restrict__ W,
                                                  float* __restrict__ C,
                                                  int D, int E) {
  __shared__ __align__(16) float As[32][132];
  __shared__ __align__(16) float Ws[32][68];
  int tid = threadIdx.x;
  int tx = tid & 15, ty = tid >> 4;
  int bm = blockIdx.y * 128, be = blockIdx.x * 64;
  int lr = tid >> 1;              // 0..127 (A row)
  int lc = (tid & 1) * 16;        // 0 or 16 (A k-offset)
  int wr = tid >> 2;              // 0..63 (W row)
  int wc = (tid & 3) * 8;         // 0,8,16,24
  float acc[8][4] = {};
  for (int k0 = 0; k0 < D; k0 += 32) {
    float4 a_[4], w_[2];
    #pragma unroll
    for (int j = 0; j < 4; ++j) a_[j] = *(const float4*)&A[(size_t)(bm + lr)*D + k0 + lc + j*4];
    #pragma unroll
    for (int j = 0; j < 2; ++j) w_[j] = *(const float4*)&W[(size_t)(be + wr)*D + k0 + wc + j*4];
    __syncthreads();
    #pragma unroll
    for (int j = 0; j < 4; ++j) {
      As[lc + j*4 + 0][lr] = a_[j].x; As[lc + j*4 + 1][lr] = a_[j].y;
      As[lc + j*4 + 2][lr] = a_[j].z; As[lc + j*4 + 3][lr] = a_[j].w;
    }
    #pragma unroll
    for (int j = 0; j < 2; ++j) {
      Ws[wc + j*4 + 0][wr] = w_[j].x; Ws[wc + j*4 + 1][wr] = w_[j].y;
      Ws[wc + j*4 + 2][wr] = w_[j].z; Ws[wc + j*4 + 3][wr] = w_[j].w;
    }
    __syncthreads();
    #pragma unroll
    for (int k = 0; k < 32; ++k) {
      float4 av0 = *(const float4*)&As[k][ty*4];
      float4 av1 = *(const float4*)&As[k][64 + ty*4];
      float4 wv  = *(const float4*)&Ws[k][tx*4];
      float ar[8] = {av0.x,av0.y,av0.z,av0.w, av1.x,av1.y,av1.z,av1.w};
      float wa[4] = {wv.x,wv.y,wv.z,wv.w};
      #pragma unroll
      for (int i = 0; i < 8; ++i)
        #pragma unroll
        for (int j = 0; j < 4; ++j)
          acc[i][j] = fmaf(ar[i], wa[j], acc[i][j]);
    }
  }
  #pragma unroll
  for (int i = 0; i < 4; ++i) {
    *(float4*)&C[(size_t)(bm + ty*4 + i)*E + be + tx*4] =
        make_float4(acc[i][0], acc[i][1], acc[i][2], acc[i][3]);
    *(float4*)&C[(size_t)(bm + 64 + ty*4 + i)*E + be + tx*4] =
        make_float4(acc[4+i][0], acc[4+i][1], acc[4+i][2], acc[4+i][3]);
  }
}

// ---------------- GEMM 64x64, K-step 32, conflict-free (out_proj) ----------------
__global__ __launch_bounds__(256, 2) void gemm_out(const float* __restrict__ A,
                                                   const float* __restrict__ W,
                                                   float* __restrict__ C,
                                                   int D, int E) {
  __shared__ __align__(16) float As[32][68];
  __shared__ __align__(16) float Ws[32][68];
  int tid = threadIdx.x;
  int tx = tid & 15, ty = tid >> 4;
  int bm = blockIdx.y * 64, be = blockIdx.x * 64;
  int ar_ = tid >> 2;             // 0..63
  int ac = (tid & 3) * 8;         // 0,8,16,24
  float acc[4][4] = {};
  for (int k0 = 0; k0 < D; k0 += 32) {
    float4 a_[2], w_[2];
    #pragma unroll
    for (int j = 0; j < 2; ++j) {
      a_[j] = *(const float4*)&A[(size_t)(bm + ar_)*D + k0 + ac + j*4];
      w_[j] = *(const float4*)&W[(size_t)(be + ar_)*D + k0 + ac + j*4];
    }
    __syncthreads();
    #pragma unroll
    for (int j = 0; j < 2; ++j) {
      As[ac + j*4 + 0][ar_] = a_[j].x; As[ac + j*4 + 1][ar_] = a_[j].y;
      As[ac + j*4 + 2][ar_] = a_[j].z; As[ac + j*4 + 3][ar_] = a_[j].w;
      Ws[ac + j*4 + 0][ar_] = w_[j].x; Ws[ac + j*4 + 1][ar_] = w_[j].y;
      Ws[ac + j*4 + 2][ar_] = w_[j].z; Ws[ac + j*4 + 3][ar_] = w_[j].w;
    }
    __syncthreads();
    #pragma unroll
    for (int k = 0; k < 32; ++k) {
      float4 av = *(const float4*)&As[k][ty*4];
      float4 wv = *(const float4*)&Ws[k][tx*4];
      float ar[4] = {av.x,av.y,av.z,av.w};
      float wa[4] = {wv.x,wv.y,wv.z,wv.w};
      #pragma unroll
      for (int i = 0; i < 4; ++i)
        #pragma unroll
        for (int j = 0; j < 4; ++j)
          acc[i][j] = fmaf(ar[i], wa[j], acc[i][j]);
    }
  }
  #pragma unroll
  for (int i = 0; i < 4; ++i)
    *(float4*)&C[(size_t)(bm + ty*4 + i)*E + be + tx*4] =
        make_float4(acc[i][0], acc[i][1], acc[i][2], acc[i][3]);
}

// ---------------- causal depthwise conv (K=4) + silu ----------------
__global__ void conv_silu_kernel(const float* __restrict__ xz, const float* __restrict__ cw,
                                 const float* __restrict__ cb, float* __restrict__ xc) {
  int idx = blockIdx.x * 256 + threadIdx.x;
  int d = idx & (DI-1);
  int t = idx >> 9;
  int l = t & (LL-1);
  float acc = cb[d];
  #pragma unroll
  for (int k = 0; k < KC; ++k) {
    int ll = l + k - (KC-1);
    if (ll >= 0) acc = fmaf(xz[(size_t)(t + k - (KC-1))*(2*DI) + d], cw[d*KC + k], acc);
  }
  xc[idx] = acc * sigmoid_f(acc);
}

// ---------------- x_proj as tiled GEMM: out[t,e] = xc[t,:] . W[e,:], E=48 ------
__global__ __launch_bounds__(256) void xproj_gemm(const float* __restrict__ xc,
                                                  const float* __restrict__ W,
                                                  float* __restrict__ out) {
  __shared__ float Xs[64][36];
  __shared__ float Ws[48][36];
  int tid = threadIdx.x;
  int tx = tid & 15, ty = tid >> 4;
  int e0 = tx * 3, t0 = ty * 4;
  int bm = blockIdx.x * 64;
  int lr = tid >> 2;
  int lc = (tid & 3) * 8;
  int we = tid >> 2;
  float acc[4][3] = {};
  for (int k0 = 0; k0 < DI; k0 += 32) {
    float4 x0 = *(const float4*)&xc[(size_t)(bm + lr)*DI + k0 + lc];
    float4 x1 = *(const float4*)&xc[(size_t)(bm + lr)*DI + k0 + lc + 4];
    *(float4*)&Xs[lr][lc]     = x0;
    *(float4*)&Xs[lr][lc + 4] = x1;
    if (we < 48) {
      float4 w0 = *(const float4*)&W[(size_t)we*DI + k0 + lc];
      float4 w1 = *(const float4*)&W[(size_t)we*DI + k0 + lc + 4];
      *(float4*)&Ws[we][lc]     = w0;
      *(float4*)&Ws[we][lc + 4] = w1;
    }
    __syncthreads();
    #pragma unroll
    for (int kk = 0; kk < 32; kk += 4) {
      float4 xv[4], wv[3];
      #pragma unroll
      for (int i = 0; i < 4; ++i) xv[i] = *(const float4*)&Xs[t0+i][kk];
      #pragma unroll
      for (int j = 0; j < 3; ++j) wv[j] = *(const float4*)&Ws[e0+j][kk];
      #pragma unroll
      for (int i = 0; i < 4; ++i)
        #pragma unroll
        for (int j = 0; j < 3; ++j) {
          acc[i][j] = fmaf(xv[i].x, wv[j].x, acc[i][j]);
          acc[i][j] = fmaf(xv[i].y, wv[j].y, acc[i][j]);
          acc[i][j] = fmaf(xv[i].z, wv[j].z, acc[i][j]);
          acc[i][j] = fmaf(xv[i].w, wv[j].w, acc[i][j]);
        }
    }
    __syncthreads();
  }
  #pragma unroll
  for (int i = 0; i < 4; ++i)
    #pragma unroll
    for (int j = 0; j < 3; ++j)
      out[(size_t)(bm + t0 + i)*XDIM + e0 + j] = acc[i][j];
}

// ---------------- chunked selective scan (delta fused) ----------------
// pass1: per-chunk local scan from h=0 -> hloc, dsum.  delta computed in-kernel.
__global__ __launch_bounds__(256) void scan_pass1(
    const float* __restrict__ xc, const float* __restrict__ xdbl,
    const float* __restrict__ dtw, const float* __restrict__ dtb,
    const float* __restrict__ A_log,
    float* __restrict__ hloc, float* __restrict__ dsum) {
  __shared__ __align__(16) float DB[CHUNK][32];   // [l][0:16 dt-part | 16:32 B]
  int bc = blockIdx.x >> 1;
  int d  = ((blockIdx.x & 1) << 8) + threadIdx.x;
  int b = bc >> 6, c = bc & (NCH-1);
  int t0 = b*LL + c*CHUNK;
  int tid = threadIdx.x;
  {
    int row = tid >> 3, q = tid & 7;
    *(float4*)&DB[row][q*4] = *(const float4*)&xdbl[(size_t)(t0+row)*XDIM + q*4];
  }
  __syncthreads();
  float4 wq[4];
  #pragma unroll
  for (int i = 0; i < 4; ++i) wq[i] = *(const float4*)&dtw[(size_t)d*RDT + i*4];
  float dtbv = dtb[d];
  float A[NST];
  #pragma unroll
  for (int n = 0; n < NST; ++n) A[n] = -__expf(A_log[d*NST + n]);
  float h[NST];
  #pragma unroll
  for (int n = 0; n < NST; ++n) h[n] = 0.f;
  float ds = 0.f;
  for (int l = 0; l < CHUNK; ++l) {
    int t = t0 + l;
    float acc = dtbv;
    #pragma unroll
    for (int i = 0; i < 4; ++i) {
      float4 a = *(const float4*)&DB[l][i*4];
      acc = fmaf(a.x, wq[i].x, acc); acc = fmaf(a.y, wq[i].y, acc);
      acc = fmaf(a.z, wq[i].z, acc); acc = fmaf(a.w, wq[i].w, acc);
    }
    float del = fmaxf(acc, 0.f) + log1pf(__expf(-fabsf(acc)));
    float xcv = xc[(size_t)t*DI + d];
    ds += del;
    float dx = del * xcv;
    #pragma unroll
    for (int n = 0; n < NST; ++n)
      h[n] = fmaf(__expf(del * A[n]), h[n], dx * DB[l][16 + n]);
  }
  #pragma unroll
  for (int n = 0; n < NST; ++n)
    hloc[((size_t)bc*NST + n)*DI + d] = h[n];
  dsum[(size_t)bc*DI + d] = ds;
}

// pass2: inter-chunk combine
__global__ __launch_bounds__(256) void scan_pass2(
    const float* __restrict__ hloc, const float* __restrict__ dsum,
    const float* __restrict__ A_log, float* __restrict__ hinit) {
  int g = blockIdx.x*256 + threadIdx.x;
  int d = g & (DI-1);
  int n = (g >> 9) & (NST-1);
  int b = g >> 13;
  float A = -__expf(A_log[d*NST + n]);
  float hc = 0.f;
  for (int c = 0; c < NCH; ++c) {
    size_t bc = (size_t)(b*NCH + c);
    hinit[(bc*NST + n)*DI + d] = hc;
    float P = __expf(A * dsum[bc*DI + d]);
    hc = fmaf(P, hc, hloc[(bc*NST + n)*DI + d]);
  }
}

// pass3: replay chunk from hinit, y = (scan + Dp*xc)*silu(z).  delta fused.
__global__ __launch_bounds__(256) void scan_pass3(
    const float* __restrict__ xc, const float* __restrict__ xdbl,
    const float* __restrict__ xz, const float* __restrict__ dtw,
    const float* __restrict__ dtb, const float* __restrict__ A_log,
    const float* __restrict__ Dp, const float* __restrict__ hinit,
    float* __restrict__ y) {
  __shared__ __align__(16) float DBC[CHUNK][48];  // [l][0:16 dt | 16:32 B | 32:48 C]
  int bc = blockIdx.x >> 1;
  int d  = ((blockIdx.x & 1) << 8) + threadIdx.x;
  int b = bc >> 6, c = bc & (NCH-1);
  int t0 = b*LL + c*CHUNK;
  int tid = threadIdx.x;
  for (int i = tid; i < CHUNK*12; i += 256) {
    int row = i / 12, q = i - row*12;
    *(float4*)&DBC[row][q*4] = *(const float4*)&xdbl[(size_t)(t0+row)*XDIM + q*4];
  }
  __syncthreads();
  float4 wq[4];
  #pragma unroll
  for (int i = 0; i < 4; ++i) wq[i] = *(const float4*)&dtw[(size_t)d*RDT + i*4];
  float dtbv = dtb[d];
  float A[NST];
  #pragma unroll
  for (int n = 0; n < NST; ++n) A[n] = -__expf(A_log[d*NST + n]);
  float h[NST];
  #pragma unroll
  for (int n = 0; n < NST; ++n) h[n] = hinit[((size_t)bc*NST + n)*DI + d];
  float Dpv = Dp[d];
  for (int l = 0; l < CHUNK; ++l) {
    int t = t0 + l;
    float acc = dtbv;
    #pragma unroll
    for (int i = 0; i < 4; ++i) {
      float4 a = *(const float4*)&DBC[l][i*4];
      acc = fmaf(a.x, wq[i].x, acc); acc = fmaf(a.y, wq[i].y, acc);
      acc = fmaf(a.z, wq[i].z, acc); acc = fmaf(a.w, wq[i].w, acc);
    }
    float del = fmaxf(acc, 0.f) + log1pf(__expf(-fabsf(acc)));
    float xcv = xc[(size_t)t*DI + d];
    float zv  = xz[(size_t)t*(2*DI) + DI + d];
    float dx = del * xcv;
    float yv = 0.f;
    #pragma unroll
    for (int n = 0; n < NST; ++n) {
      h[n] = fmaf(__expf(del * A[n]), h[n], dx * DBC[l][16 + n]);
      yv = fmaf(h[n], DBC[l][32 + n], yv);
    }
    yv = fmaf(Dpv, xcv, yv);
    y[(size_t)t*DI + d] = yv * zv * sigmoid_f(zv);
  }
}

// ---------------- pool stage 1: partial sums over L ----------------
__global__ void pool1_kernel(const float* __restrict__ ln, float* __restrict__ part) {
  int blk = blockIdx.x;
  int b = blk >> 4, c = blk & 15;
  int d = threadIdx.x;
  const float* base = ln + (size_t)b*LL*DM + (size_t)c*128*DM + d;
  float s = 0.f;
  #pragma unroll 8
  for (int l = 0; l < 128; ++l) s += base[(size_t)l*DM];
  part[(size_t)blk*DM + d] = s;
}

// ---------------- pool stage 2 + decode ----------------
__global__ void pool_decode_kernel(const float* __restrict__ part, const float* __restrict__ dw,
                                   const float* __restrict__ db, float* __restrict__ out) {
  int b = blockIdx.x, d = threadIdx.x;
  __shared__ float pooled[DM];
  float s = 0.f;
  #pragma unroll
  for (int c = 0; c < 16; ++c) s += part[(size_t)(b*16 + c)*DM + d];
  pooled[d] = s * (1.0f/LL);
  __syncthreads();
  if (d < DOUT) {
    float acc = db[d];
    for (int m = 0; m < DM; ++m) acc = fmaf(pooled[m], dw[d*DM + m], acc);
    out[b*DOUT + d] = acc;
  }
}

extern "C" void kernel_launch(void* const* d_in, const int* in_sizes, int n_in,
                              void* d_out, int out_size, void* d_ws, size_t ws_size,
                              hipStream_t stream) {
  const int*   ids     = (const int*)d_in[0];
  const float* emb     = (const float*)d_in[1];
  const float* norm_w  = (const float*)d_in[2];
  const float* norm_b  = (const float*)d_in[3];
  const float* in_w    = (const float*)d_in[4];
  const float* conv_w  = (const float*)d_in[5];
  const float* conv_b  = (const float*)d_in[6];
  const float* xp_w    = (const float*)d_in[7];
  const float* dt_w    = (const float*)d_in[8];
  const float* dt_b    = (const float*)d_in[9];
  const float* A_log   = (const float*)d_in[10];
  const float* Dp      = (const float*)d_in[11];
  const float* out_w   = (const float*)d_in[12];
  const float* normf_w = (const float*)d_in[13];
  const float* normf_b = (const float*)d_in[14];
  const float* dec_w   = (const float*)d_in[15];
  const float* dec_b   = (const float*)d_in[16];
  float* out = (float*)d_out;

  float* ws = (float*)d_ws;
  float* hidden   = ws; ws += TOK*DM;
  float* residual = ws; ws += TOK*DM;
  float* hbuf     = ws; ws += TOK*DM;
  float* xzbuf    = ws; ws += (size_t)TOK*2*DI;
  float* xcbuf    = ws; ws += TOK*DI;
  float* xdblbuf  = ws; ws += TOK*XDIM;
  float* ybuf     = ws; ws += TOK*DI;
  float* hlocbuf  = ws; ws += (size_t)BB*NCH*NST*DI;
  float* hinitbuf = ws; ws += (size_t)BB*NCH*NST*DI;
  float* dsumbuf  = ws; ws += (size_t)BB*NCH*DI;
  float* partbuf  = ws; ws += (size_t)BB*16*DM;

  embed_kernel<<<TOK, DM, 0, stream>>>(ids, emb, hidden);

  for (int i = 0; i < NLAY; ++i) {
    add_ln_kernel<<<TOK, DM, 0, stream>>>(residual, hidden,
                                          norm_w + i*DM, norm_b + i*DM, hbuf, i == 0);
    // in_proj: [TOK,DM] x [2DI,DM]^T -> [TOK,2DI]; grid (1024/64, 4096/128) = 16x32
    gemm_in<<<dim3((2*DI)/64, TOK/128), 256, 0, stream>>>(
        hbuf, in_w + (size_t)i*2*DI*DM, xzbuf, DM, 2*DI);
    conv_silu_kernel<<<(TOK*DI)/256, 256, 0, stream>>>(
        xzbuf, conv_w + i*DI*KC, conv_b + i*DI, xcbuf);
    xproj_gemm<<<TOK/64, 256, 0, stream>>>(
        xcbuf, xp_w + (size_t)i*XDIM*DI, xdblbuf);
    scan_pass1<<<BB*NCH*(DI/256), 256, 0, stream>>>(
        xcbuf, xdblbuf, dt_w + (size_t)i*DI*RDT, dt_b + i*DI,
        A_log + (size_t)i*DI*NST, hlocbuf, dsumbuf);
    scan_pass2<<<(BB*NST*DI)/256, 256, 0, stream>>>(
        hlocbuf, dsumbuf, A_log + (size_t)i*DI*NST, hinitbuf);
    scan_pass3<<<BB*NCH*(DI/256), 256, 0, stream>>>(
        xcbuf, xdblbuf, xzbuf, dt_w + (size_t)i*DI*RDT, dt_b + i*DI,
        A_log + (size_t)i*DI*NST, Dp + i*DI, hinitbuf, ybuf);
    // out_proj: [TOK,DI] x [DM,DI]^T -> [TOK,DM]; grid (256/64, 4096/64) = 4x64
    gemm_out<<<dim3(DM/64, TOK/64), 256, 0, stream>>>(
        ybuf, out_w + (size_t)i*DM*DI, hidden, DI, DM);
  }

  add_ln_kernel<<<TOK, DM, 0, stream>>>(residual, hidden, normf_w, normf_b, hbuf, 0);
  pool1_kernel<<<BB*16, DM, 0, stream>>>(hbuf, partbuf);
  pool_decode_kernel<<<BB, DM, 0, stream>>>(partbuf, dec_w, dec_b, out);
}

// Round 5
// 609.011 us; speedup vs baseline: 7.7848x; 1.1643x over previous
//
#include <hip/hip_runtime.h>
#include <hip/hip_bf16.h>

#define BB 2
#define LL 2048
#define DM 256
#define DI 512
#define NST 16
#define RDT 16
#define KC 4
#define NLAY 4
#define DOUT 10
#define XDIM 48            // R + 2N
#define TOK (BB*LL)        // 4096
#define EPSF 1e-5f
#define CHUNK 32
#define NCH (LL/CHUNK)     // 64

typedef __bf16 bf16x8 __attribute__((ext_vector_type(8)));
typedef float  f32x4  __attribute__((ext_vector_type(4)));

__device__ __forceinline__ float sigmoid_f(float x) { return 1.0f / (1.0f + __expf(-x)); }

// ---------------- embedding ----------------
__global__ void embed_kernel(const int* __restrict__ ids, const float* __restrict__ emb,
                             float* __restrict__ hidden) {
  int t = blockIdx.x, d = threadIdx.x;
  hidden[t*DM + d] = emb[ids[t]*DM + d];
}

// ---------------- weight cast fp32 -> bf16 (once per call) ----------------
__global__ void cast_w_kernel(const float* __restrict__ a, const float* __restrict__ b,
                              __bf16* __restrict__ ab, __bf16* __restrict__ bb,
                              int na, int nb) {
  int stride = gridDim.x * 256;
  for (int i = blockIdx.x*256 + threadIdx.x; i < na; i += stride) ab[i] = (__bf16)a[i];
  for (int i = blockIdx.x*256 + threadIdx.x; i < nb; i += stride) bb[i] = (__bf16)b[i];
}

// ---------------- residual add + layernorm (emits fp32 + bf16) ----------------
__global__ void add_ln_kernel(float* __restrict__ residual, const float* __restrict__ hidden,
                              const float* __restrict__ w, const float* __restrict__ bia,
                              float* __restrict__ out, __bf16* __restrict__ out_bf,
                              int first) {
  int t = blockIdx.x, d = threadIdx.x;
  __shared__ float ws8[8];
  float r = hidden[t*DM + d];
  if (!first) r += residual[t*DM + d];
  residual[t*DM + d] = r;
  float s = r;
  #pragma unroll
  for (int o = 32; o; o >>= 1) s += __shfl_down(s, o);
  if ((d & 63) == 0) ws8[d >> 6] = s;
  __syncthreads();
  float mean = (ws8[0] + ws8[1] + ws8[2] + ws8[3]) * (1.0f/DM);
  float diff = r - mean;
  float q = diff * diff;
  #pragma unroll
  for (int o = 32; o; o >>= 1) q += __shfl_down(q, o);
  if ((d & 63) == 0) ws8[4 + (d >> 6)] = q;
  __syncthreads();
  float var = (ws8[4] + ws8[5] + ws8[6] + ws8[7]) * (1.0f/DM);
  float v = diff * rsqrtf(var + EPSF) * w[d] + bia[d];
  out[t*DM + d] = v;
  out_bf[t*DM + d] = (__bf16)v;
}

// ---------------- bf16 MFMA GEMM: C[M,E] = A[M,K] x W[E,K]^T ----------------
// Block 256 thr (4 waves). Tile M=64 (wave wv owns rows wv*16..+15), E-tile 64, K-chunk 32.
// LDS staged in MFMA fragment order: slot (sub*64 + lane)*8, lane = (k/8)*16 + row.
__global__ __launch_bounds__(256, 2) void gemm_bf16(const __bf16* __restrict__ A,
                                                    const __bf16* __restrict__ W,
                                                    float* __restrict__ C,
                                                    int K, int E) {
  __shared__ __bf16 As[4*64*8];
  __shared__ __bf16 Ws[4*64*8];
  int tid = threadIdx.x;
  int lane = tid & 63, wv = tid >> 6;
  int bm = blockIdx.y * 64, be = blockIdx.x * 64;
  int ss = tid >> 6, sq = (tid >> 4) & 3, sm = tid & 15;   // staging: subtile, k-quad, row
  f32x4 acc[4];
  #pragma unroll
  for (int et = 0; et < 4; ++et) acc[et] = (f32x4){0.f, 0.f, 0.f, 0.f};
  for (int k0 = 0; k0 < K; k0 += 32) {
    bf16x8 av = *(const bf16x8*)&A[(size_t)(bm + ss*16 + sm)*K + k0 + sq*8];
    bf16x8 wvv = *(const bf16x8*)&W[(size_t)(be + ss*16 + sm)*K + k0 + sq*8];
    __syncthreads();
    *(bf16x8*)&As[((ss*4 + sq)*16 + sm)*8] = av;
    *(bf16x8*)&Ws[((ss*4 + sq)*16 + sm)*8] = wvv;
    __syncthreads();
    bf16x8 af = *(const bf16x8*)&As[(wv*64 + lane)*8];
    #pragma unroll
    for (int et = 0; et < 4; ++et) {
      bf16x8 bfr = *(const bf16x8*)&Ws[(et*64 + lane)*8];
      acc[et] = __builtin_amdgcn_mfma_f32_16x16x32_bf16(af, bfr, acc[et], 0, 0, 0);
    }
  }
  int row0 = bm + wv*16 + (lane >> 4)*4;
  int col0 = be + (lane & 15);
  #pragma unroll
  for (int et = 0; et < 4; ++et)
    #pragma unroll
    for (int r = 0; r < 4; ++r)
      C[(size_t)(row0 + r)*E + col0 + et*16] = acc[et][r];
}

// ---------------- causal depthwise conv (K=4) + silu ----------------
__global__ void conv_silu_kernel(const float* __restrict__ xz, const float* __restrict__ cw,
                                 const float* __restrict__ cb, float* __restrict__ xc) {
  int idx = blockIdx.x * 256 + threadIdx.x;
  int d = idx & (DI-1);
  int t = idx >> 9;
  int l = t & (LL-1);
  float acc = cb[d];
  #pragma unroll
  for (int k = 0; k < KC; ++k) {
    int ll = l + k - (KC-1);
    if (ll >= 0) acc = fmaf(xz[(size_t)(t + k - (KC-1))*(2*DI) + d], cw[d*KC + k], acc);
  }
  xc[idx] = acc * sigmoid_f(acc);
}

// ---------------- x_proj as tiled GEMM: out[t,e] = xc[t,:] . W[e,:], E=48 ------
__global__ __launch_bounds__(256) void xproj_gemm(const float* __restrict__ xc,
                                                  const float* __restrict__ W,
                                                  float* __restrict__ out) {
  __shared__ float Xs[64][36];
  __shared__ float Ws[48][36];
  int tid = threadIdx.x;
  int tx = tid & 15, ty = tid >> 4;
  int e0 = tx * 3, t0 = ty * 4;
  int bm = blockIdx.x * 64;
  int lr = tid >> 2;
  int lc = (tid & 3) * 8;
  int we = tid >> 2;
  float acc[4][3] = {};
  for (int k0 = 0; k0 < DI; k0 += 32) {
    float4 x0 = *(const float4*)&xc[(size_t)(bm + lr)*DI + k0 + lc];
    float4 x1 = *(const float4*)&xc[(size_t)(bm + lr)*DI + k0 + lc + 4];
    *(float4*)&Xs[lr][lc]     = x0;
    *(float4*)&Xs[lr][lc + 4] = x1;
    if (we < 48) {
      float4 w0 = *(const float4*)&W[(size_t)we*DI + k0 + lc];
      float4 w1 = *(const float4*)&W[(size_t)we*DI + k0 + lc + 4];
      *(float4*)&Ws[we][lc]     = w0;
      *(float4*)&Ws[we][lc + 4] = w1;
    }
    __syncthreads();
    #pragma unroll
    for (int kk = 0; kk < 32; kk += 4) {
      float4 xv[4], wv[3];
      #pragma unroll
      for (int i = 0; i < 4; ++i) xv[i] = *(const float4*)&Xs[t0+i][kk];
      #pragma unroll
      for (int j = 0; j < 3; ++j) wv[j] = *(const float4*)&Ws[e0+j][kk];
      #pragma unroll
      for (int i = 0; i < 4; ++i)
        #pragma unroll
        for (int j = 0; j < 3; ++j) {
          acc[i][j] = fmaf(xv[i].x, wv[j].x, acc[i][j]);
          acc[i][j] = fmaf(xv[i].y, wv[j].y, acc[i][j]);
          acc[i][j] = fmaf(xv[i].z, wv[j].z, acc[i][j]);
          acc[i][j] = fmaf(xv[i].w, wv[j].w, acc[i][j]);
        }
    }
    __syncthreads();
  }
  #pragma unroll
  for (int i = 0; i < 4; ++i)
    #pragma unroll
    for (int j = 0; j < 3; ++j)
      out[(size_t)(bm + t0 + i)*XDIM + e0 + j] = acc[i][j];
}

// ---------------- chunked selective scan (delta fused) ----------------
// hloc/hinit layout: [((b*NST + n)*NCH + c)]*DI + d   (c-stride = 2KB for pass2 locality)
__global__ __launch_bounds__(256) void scan_pass1(
    const float* __restrict__ xc, const float* __restrict__ xdbl,
    const float* __restrict__ dtw, const float* __restrict__ dtb,
    const float* __restrict__ A_log,
    float* __restrict__ hloc, float* __restrict__ dsum) {
  __shared__ __align__(16) float DB[CHUNK][32];   // [l][0:16 dt-part | 16:32 B]
  int bc = blockIdx.x >> 1;
  int d  = ((blockIdx.x & 1) << 8) + threadIdx.x;
  int b = bc >> 6, c = bc & (NCH-1);
  int t0 = b*LL + c*CHUNK;
  int tid = threadIdx.x;
  {
    int row = tid >> 3, q = tid & 7;
    *(float4*)&DB[row][q*4] = *(const float4*)&xdbl[(size_t)(t0+row)*XDIM + q*4];
  }
  __syncthreads();
  float4 wq[4];
  #pragma unroll
  for (int i = 0; i < 4; ++i) wq[i] = *(const float4*)&dtw[(size_t)d*RDT + i*4];
  float dtbv = dtb[d];
  float A[NST];
  #pragma unroll
  for (int n = 0; n < NST; ++n) A[n] = -__expf(A_log[d*NST + n]);
  float h[NST];
  #pragma unroll
  for (int n = 0; n < NST; ++n) h[n] = 0.f;
  float ds = 0.f;
  for (int l = 0; l < CHUNK; ++l) {
    int t = t0 + l;
    float acc = dtbv;
    #pragma unroll
    for (int i = 0; i < 4; ++i) {
      float4 a = *(const float4*)&DB[l][i*4];
      acc = fmaf(a.x, wq[i].x, acc); acc = fmaf(a.y, wq[i].y, acc);
      acc = fmaf(a.z, wq[i].z, acc); acc = fmaf(a.w, wq[i].w, acc);
    }
    float del = fmaxf(acc, 0.f) + log1pf(__expf(-fabsf(acc)));
    float xcv = xc[(size_t)t*DI + d];
    ds += del;
    float dx = del * xcv;
    #pragma unroll
    for (int n = 0; n < NST; ++n)
      h[n] = fmaf(__expf(del * A[n]), h[n], dx * DB[l][16 + n]);
  }
  #pragma unroll
  for (int n = 0; n < NST; ++n)
    hloc[((size_t)(b*NST + n)*NCH + c)*DI + d] = h[n];
  dsum[(size_t)bc*DI + d] = ds;
}

__global__ __launch_bounds__(256) void scan_pass2(
    const float* __restrict__ hloc, const float* __restrict__ dsum,
    const float* __restrict__ A_log, float* __restrict__ hinit) {
  int g = blockIdx.x*256 + threadIdx.x;
  int d = g & (DI-1);
  int n = (g >> 9) & (NST-1);
  int b = g >> 13;
  float A = -__expf(A_log[d*NST + n]);
  float hc = 0.f;
  size_t base = (size_t)(b*NST + n)*NCH*DI + d;
  for (int c = 0; c < NCH; ++c) {
    hinit[base + (size_t)c*DI] = hc;
    float P = __expf(A * dsum[(size_t)(b*NCH + c)*DI + d]);
    hc = fmaf(P, hc, hloc[base + (size_t)c*DI]);
  }
}

__global__ __launch_bounds__(256) void scan_pass3(
    const float* __restrict__ xc, const float* __restrict__ xdbl,
    const float* __restrict__ xz, const float* __restrict__ dtw,
    const float* __restrict__ dtb, const float* __restrict__ A_log,
    const float* __restrict__ Dp, const float* __restrict__ hinit,
    __bf16* __restrict__ y) {
  __shared__ __align__(16) float DBC[CHUNK][48];  // [l][0:16 dt | 16:32 B | 32:48 C]
  int bc = blockIdx.x >> 1;
  int d  = ((blockIdx.x & 1) << 8) + threadIdx.x;
  int b = bc >> 6, c = bc & (NCH-1);
  int t0 = b*LL + c*CHUNK;
  int tid = threadIdx.x;
  for (int i = tid; i < CHUNK*12; i += 256) {
    int row = i / 12, q = i - row*12;
    *(float4*)&DBC[row][q*4] = *(const float4*)&xdbl[(size_t)(t0+row)*XDIM + q*4];
  }
  __syncthreads();
  float4 wq[4];
  #pragma unroll
  for (int i = 0; i < 4; ++i) wq[i] = *(const float4*)&dtw[(size_t)d*RDT + i*4];
  float dtbv = dtb[d];
  float A[NST];
  #pragma unroll
  for (int n = 0; n < NST; ++n) A[n] = -__expf(A_log[d*NST + n]);
  float h[NST];
  #pragma unroll
  for (int n = 0; n < NST; ++n) h[n] = hinit[((size_t)(b*NST + n)*NCH + c)*DI + d];
  float Dpv = Dp[d];
  for (int l = 0; l < CHUNK; ++l) {
    int t = t0 + l;
    float acc = dtbv;
    #pragma unroll
    for (int i = 0; i < 4; ++i) {
      float4 a = *(const float4*)&DBC[l][i*4];
      acc = fmaf(a.x, wq[i].x, acc); acc = fmaf(a.y, wq[i].y, acc);
      acc = fmaf(a.z, wq[i].z, acc); acc = fmaf(a.w, wq[i].w, acc);
    }
    float del = fmaxf(acc, 0.f) + log1pf(__expf(-fabsf(acc)));
    float xcv = xc[(size_t)t*DI + d];
    float zv  = xz[(size_t)t*(2*DI) + DI + d];
    float dx = del * xcv;
    float yv = 0.f;
    #pragma unroll
    for (int n = 0; n < NST; ++n) {
      h[n] = fmaf(__expf(del * A[n]), h[n], dx * DBC[l][16 + n]);
      yv = fmaf(h[n], DBC[l][32 + n], yv);
    }
    yv = fmaf(Dpv, xcv, yv);
    y[(size_t)t*DI + d] = (__bf16)(yv * zv * sigmoid_f(zv));
  }
}

// ---------------- pool stage 1: partial sums over L (64 blocks) ----------------
__global__ void pool1_kernel(const float* __restrict__ ln, float* __restrict__ part) {
  int blk = blockIdx.x;             // b*32 + c
  int b = blk >> 5, c = blk & 31;
  int d = threadIdx.x;
  const float* base = ln + (size_t)b*LL*DM + (size_t)c*64*DM + d;
  float s = 0.f;
  #pragma unroll 8
  for (int l = 0; l < 64; ++l) s += base[(size_t)l*DM];
  part[(size_t)blk*DM + d] = s;
}

// ---------------- pool stage 2 + decode ----------------
__global__ void pool_decode_kernel(const float* __restrict__ part, const float* __restrict__ dw,
                                   const float* __restrict__ db, float* __restrict__ out) {
  int b = blockIdx.x, d = threadIdx.x;
  __shared__ float pooled[DM];
  float s = 0.f;
  #pragma unroll
  for (int c = 0; c < 32; ++c) s += part[(size_t)(b*32 + c)*DM + d];
  pooled[d] = s * (1.0f/LL);
  __syncthreads();
  if (d < DOUT) {
    float acc = db[d];
    for (int m = 0; m < DM; ++m) acc = fmaf(pooled[m], dw[d*DM + m], acc);
    out[b*DOUT + d] = acc;
  }
}

extern "C" void kernel_launch(void* const* d_in, const int* in_sizes, int n_in,
                              void* d_out, int out_size, void* d_ws, size_t ws_size,
                              hipStream_t stream) {
  const int*   ids     = (const int*)d_in[0];
  const float* emb     = (const float*)d_in[1];
  const float* norm_w  = (const float*)d_in[2];
  const float* norm_b  = (const float*)d_in[3];
  const float* in_w    = (const float*)d_in[4];
  const float* conv_w  = (const float*)d_in[5];
  const float* conv_b  = (const float*)d_in[6];
  const float* xp_w    = (const float*)d_in[7];
  const float* dt_w    = (const float*)d_in[8];
  const float* dt_b    = (const float*)d_in[9];
  const float* A_log   = (const float*)d_in[10];
  const float* Dp      = (const float*)d_in[11];
  const float* out_w   = (const float*)d_in[12];
  const float* normf_w = (const float*)d_in[13];
  const float* normf_b = (const float*)d_in[14];
  const float* dec_w   = (const float*)d_in[15];
  const float* dec_b   = (const float*)d_in[16];
  float* out = (float*)d_out;

  float* ws = (float*)d_ws;
  float* hidden   = ws; ws += TOK*DM;
  float* residual = ws; ws += TOK*DM;
  float* hbuf     = ws; ws += TOK*DM;
  float* xzbuf    = ws; ws += (size_t)TOK*2*DI;
  float* xcbuf    = ws; ws += TOK*DI;
  float* xdblbuf  = ws; ws += TOK*XDIM;
  float* hlocbuf  = ws; ws += (size_t)BB*NCH*NST*DI;
  float* hinitbuf = ws; ws += (size_t)BB*NCH*NST*DI;
  float* dsumbuf  = ws; ws += (size_t)BB*NCH*DI;
  float* partbuf  = ws; ws += (size_t)BB*32*DM;
  __bf16* hbuf_bf = (__bf16*)ws; ws += TOK*DM/2;
  __bf16* ybuf_bf = (__bf16*)ws; ws += TOK*DI/2;
  __bf16* inw_bf  = (__bf16*)ws; ws += (size_t)NLAY*2*DI*DM/2;
  __bf16* outw_bf = (__bf16*)ws; ws += (size_t)NLAY*DM*DI/2;

  const int n_inw = NLAY*2*DI*DM, n_outw = NLAY*DM*DI;
  cast_w_kernel<<<2048, 256, 0, stream>>>(in_w, out_w, inw_bf, outw_bf, n_inw, n_outw);
  embed_kernel<<<TOK, DM, 0, stream>>>(ids, emb, hidden);

  for (int i = 0; i < NLAY; ++i) {
    add_ln_kernel<<<TOK, DM, 0, stream>>>(residual, hidden,
                                          norm_w + i*DM, norm_b + i*DM, hbuf, hbuf_bf, i == 0);
    // in_proj: [TOK,DM(bf16)] x [2DI,DM(bf16)]^T -> xz fp32; grid (1024/64, 4096/64)
    gemm_bf16<<<dim3((2*DI)/64, TOK/64), 256, 0, stream>>>(
        hbuf_bf, inw_bf + (size_t)i*2*DI*DM, xzbuf, DM, 2*DI);
    conv_silu_kernel<<<(TOK*DI)/256, 256, 0, stream>>>(
        xzbuf, conv_w + i*DI*KC, conv_b + i*DI, xcbuf);
    xproj_gemm<<<TOK/64, 256, 0, stream>>>(
        xcbuf, xp_w + (size_t)i*XDIM*DI, xdblbuf);
    scan_pass1<<<BB*NCH*(DI/256), 256, 0, stream>>>(
        xcbuf, xdblbuf, dt_w + (size_t)i*DI*RDT, dt_b + i*DI,
        A_log + (size_t)i*DI*NST, hlocbuf, dsumbuf);
    scan_pass2<<<(BB*NST*DI)/256, 256, 0, stream>>>(
        hlocbuf, dsumbuf, A_log + (size_t)i*DI*NST, hinitbuf);
    scan_pass3<<<BB*NCH*(DI/256), 256, 0, stream>>>(
        xcbuf, xdblbuf, xzbuf, dt_w + (size_t)i*DI*RDT, dt_b + i*DI,
        A_log + (size_t)i*DI*NST, Dp + i*DI, hinitbuf, ybuf_bf);
    // out_proj: [TOK,DI(bf16)] x [DM,DI(bf16)]^T -> hidden fp32; grid (256/64, 4096/64)
    gemm_bf16<<<dim3(DM/64, TOK/64), 256, 0, stream>>>(
        ybuf_bf, outw_bf + (size_t)i*DM*DI, hidden, DI, DM);
  }

  add_ln_kernel<<<TOK, DM, 0, stream>>>(residual, hidden, normf_w, normf_b, hbuf, hbuf_bf, 0);
  pool1_kernel<<<BB*32, DM, 0, stream>>>(hbuf, partbuf);
  pool_decode_kernel<<<BB, DM, 0, stream>>>(partbuf, dec_w, dec_b, out);
}